// Round 1
// baseline (44.771 us; speedup 1.0000x reference)
//
#include <hip/hip_runtime.h>
#include <math.h>

#define L_BANDS 28
#define H 1024
#define W 1024

// Gather formulation of CASSI forward:
//   out[Y, X] = sum_l  mask[Y-dy_l, X-dx_l] * x[l, Y-dy_l, X-dx_l]
// Offsets mirror the reference's detached numpy math:
//   phi = phi_deg * pi/180 (float64); dx = rint(s*cos(phi) - min); dy likewise.
// Offsets are computed per-block by thread 0 in double precision (28 elems,
// two passes, no local arrays -> no scratch allocation).
__global__ void cassi_fwd_gather(const float* __restrict__ x,
                                 const float* __restrict__ mask,
                                 const float* __restrict__ phi_deg,
                                 const float* __restrict__ s_nom,
                                 float* __restrict__ out,
                                 int out_size) {
    __shared__ int s_dx[L_BANDS];
    __shared__ int s_dy[L_BANDS];
    __shared__ int s_Wp;

    if (threadIdx.x == 0) {
        double phi = (double)phi_deg[0] * 3.14159265358979323846 / 180.0;
        double c = cos(phi);
        double sn = sin(phi);
        // pass 1: mins
        double dxmin = 1e300, dymin = 1e300;
        for (int l = 0; l < L_BANDS; ++l) {
            double s = (double)s_nom[l];
            dxmin = fmin(dxmin, s * c);
            dymin = fmin(dymin, s * sn);
        }
        // pass 2: integer offsets + maxes
        int dxmax = 0, dymax = 0;
        for (int l = 0; l < L_BANDS; ++l) {
            double s = (double)s_nom[l];
            int dx = (int)rint(s * c - dxmin);
            int dy = (int)rint(s * sn - dymin);
            s_dx[l] = dx;
            s_dy[l] = dy;
            dxmax = max(dxmax, dx);
            dymax = max(dymax, dy);
        }
        s_Wp = W + dxmax;
        (void)dymax;
    }
    __syncthreads();

    const int Wp = s_Wp;
    int idx = blockIdx.x * blockDim.x + threadIdx.x;
    if (idx >= out_size) return;

    int Y = idx / Wp;
    int X = idx - Y * Wp;

    float acc = 0.0f;
#pragma unroll
    for (int l = 0; l < L_BANDS; ++l) {
        int h = Y - s_dy[l];
        int w = X - s_dx[l];
        if ((unsigned)h < (unsigned)H && (unsigned)w < (unsigned)W) {
            int p = h * W + w;
            acc = fmaf(mask[p], x[l * (H * W) + p], acc);
        }
    }
    out[idx] = acc;
}

extern "C" void kernel_launch(void* const* d_in, const int* in_sizes, int n_in,
                              void* d_out, int out_size, void* d_ws, size_t ws_size,
                              hipStream_t stream) {
    const float* x = (const float*)d_in[0];      // [1, 28, 1024, 1024]
    const float* mask = (const float*)d_in[1];   // [1024, 1024]
    const float* phi = (const float*)d_in[2];    // [1]
    const float* s_nom = (const float*)d_in[3];  // [28]
    float* out = (float*)d_out;                  // [1, Hp, Wp]

    const int threads = 256;
    const int blocks = (out_size + threads - 1) / threads;
    cassi_fwd_gather<<<blocks, threads, 0, stream>>>(x, mask, phi, s_nom, out, out_size);
}